// Round 18
// baseline (517.767 us; speedup 1.0000x reference)
//
#include <hip/hip_runtime.h>
#include <stdint.h>

// ============================================================================
// CPC forward on MI355X (gfx950).
// R16: int8+sdot4 GRU (~165us). R17: k_cpc grid reorder+alias: 245->234us,
// FETCH 298->99MB — latency-bound, not BW. R18 (k_cpc only):
//  (1) c-tile LDS staging DROPPED (no intra-block reuse; direct A-frag
//      gathers, L2-hot via kk-fastest grid);
//  (2) Wk staged in 2 half-K phases -> preds barriers 16->4;
//  (3) logits MFMA operand-swapped: S[s][t]=mfma(z,P) -> lane owns t-column,
//      online LSE/pos/neg THREAD-LOCAL (no shfl chains, no z staging, no
//      barriers); 2-step shfl + 4KB LDS combine at end;
//  (4) LDS 51.7->34KB -> 4 blocks/CU; barriers ~22->7.
// ============================================================================

typedef _Float16 f16;
typedef __attribute__((ext_vector_type(2))) _Float16 f16x2;
typedef __attribute__((ext_vector_type(8))) _Float16 f16x8;
typedef __attribute__((ext_vector_type(4))) float f32x4;

__device__ __forceinline__ f16x2 u2h(unsigned int x) { return __builtin_bit_cast(f16x2, x); }
__device__ __forceinline__ float sigm_(float x) { return __builtin_amdgcn_rcpf(1.f + __expf(-x)); }
__device__ __forceinline__ float tanh_(float x) { return 1.f - 2.f * __builtin_amdgcn_rcpf(__expf(2.f * x) + 1.f); }

#define NTOT_LOSS 374784.0f  // 12 * 128 * 244

// ---------------------------------------------------------------------------
// K0: weight conversion. W_hh -> int8 chunk-major + per-row scale (R16).
// ---------------------------------------------------------------------------
__global__ void k_prep(const float* __restrict__ w1, const float* __restrict__ w2,
                       const float* __restrict__ wih, const float* __restrict__ whh,
                       const float* __restrict__ wkw,
                       f16* __restrict__ w1T, f16* __restrict__ w2T, f16* __restrict__ wihF,
                       uint8_t* __restrict__ whhQ, float* __restrict__ wsc,
                       f16* __restrict__ wkT, float* __restrict__ accb) {
  const int stride = gridDim.x * blockDim.x;
  const int tid = blockIdx.x * blockDim.x + threadIdx.x;
  if (tid == 0) { accb[0] = 0.f; accb[1] = 0.f; }
  for (int i = tid; i < 65536; i += stride) { int n = i >> 8, k = i & 255; w1T[i] = (f16)w1[k * 256 + n]; }
  for (int i = tid; i < 32768; i += stride) { int n = i >> 8, k = i & 255; w2T[i] = (f16)w2[k * 128 + n]; }
  for (int i = tid; i < 98304; i += stride) wihF[i] = (f16)wih[i];
  if (tid < 768) {
    const float* row = whh + (size_t)tid * 256;
    float amax = 0.f;
    for (int k = 0; k < 256; ++k) amax = fmaxf(amax, fabsf(row[k]));
    const float rs = 127.f / fmaxf(amax, 1e-20f);
    wsc[tid] = fmaxf(amax, 1e-20f) / (127.f * 127.f);
    for (int jq = 0; jq < 16; ++jq) {
      uint32_t words[4];
      for (int w32 = 0; w32 < 4; ++w32) {
        uint32_t p = 0;
        for (int e = 0; e < 4; ++e) {
          const int k = jq * 16 + w32 * 4 + e;
          const int q = (int)rintf(row[k] * rs);
          p |= ((uint32_t)(uint8_t)(int8_t)q) << (8 * e);
        }
        words[w32] = p;
      }
      *(uint4*)(whhQ + ((size_t)jq * 768 + tid) * 16) =
          make_uint4(words[0], words[1], words[2], words[3]);
    }
  }
  for (int i = tid; i < 393216; i += stride) {
    int kk = i >> 15, rem = i & 32767, d = rem >> 8, c = rem & 255;
    wkT[i] = (f16)wkw[(kk << 15) + c * 128 + d];
  }
}

// ---------------------------------------------------------------------------
// Generic 64x64-tile f16 MFMA GEMM (R2 version).
// ---------------------------------------------------------------------------
template <int KTOT, bool AF32, bool RELU>
__global__ __launch_bounds__(256) void k_gemm64(const void* __restrict__ Aptr,
                                                const f16* __restrict__ BT,
                                                const float* __restrict__ bias,
                                                f16* __restrict__ out, const int NT) {
  __shared__ __align__(16) f16 Al[64][40];
  __shared__ __align__(16) f16 Bl[64][40];
  const int m0 = blockIdx.x * 64;
  const int n0 = blockIdx.y * 64;
  const int t = threadIdx.x;
  const int w = t >> 6, l = t & 63, lr = l & 15, lg = l >> 4;
  const int arow = t >> 2, akq = (t & 3) * 8;
  f32x4 acc[4] = {};
  for (int ks = 0; ks < KTOT / 32; ++ks) {
    const int kc = ks * 32;
    __syncthreads();
    if constexpr (AF32) {
      const float* src = (const float*)Aptr + (size_t)(m0 + arow) * KTOT + kc + akq;
      float4 v0 = *(const float4*)src;
      float4 v1 = *(const float4*)(src + 4);
      f16x8 hv = {(f16)v0.x, (f16)v0.y, (f16)v0.z, (f16)v0.w,
                  (f16)v1.x, (f16)v1.y, (f16)v1.z, (f16)v1.w};
      *(f16x8*)&Al[arow][akq] = hv;
    } else {
      const f16* src = (const f16*)Aptr + (size_t)(m0 + arow) * KTOT + kc + akq;
      *(f16x8*)&Al[arow][akq] = *(const f16x8*)src;
    }
    *(f16x8*)&Bl[arow][akq] = *(const f16x8*)(BT + (size_t)(n0 + arow) * KTOT + kc + akq);
    __syncthreads();
    f16x8 af = *(const f16x8*)&Al[16 * w + lr][lg * 8];
#pragma unroll
    for (int nt = 0; nt < 4; ++nt) {
      f16x8 bf = *(const f16x8*)&Bl[nt * 16 + lr][lg * 8];
      acc[nt] = __builtin_amdgcn_mfma_f32_16x16x32_f16(af, bf, acc[nt], 0, 0, 0);
    }
  }
#pragma unroll
  for (int nt = 0; nt < 4; ++nt) {
    const int n = n0 + nt * 16 + lr;
    const float bb = bias[n];
#pragma unroll
    for (int r = 0; r < 4; ++r) {
      const int m = m0 + 16 * w + lg * 4 + r;
      float v = acc[nt][r] + bb;
      if (RELU) v = fmaxf(v, 0.f);
      out[(size_t)m * NT + n] = (f16)v;
    }
  }
}

// ---------------------------------------------------------------------------
// K2: z = l2norm(h1 @ w2T + b2). (R2 version)
// ---------------------------------------------------------------------------
__global__ __launch_bounds__(256) void k_enc2(const f16* __restrict__ A, const f16* __restrict__ BT,
                                              const float* __restrict__ bias,
                                              float* __restrict__ zf32, f16* __restrict__ zf16) {
  __shared__ __align__(16) f16 Al[64][40];
  __shared__ __align__(16) f16 Bl[128][40];
  const int m0 = blockIdx.x * 64;
  const int t = threadIdx.x;
  const int w = t >> 6, l = t & 63, lr = l & 15, lg = l >> 4;
  const int arow = t >> 2, akq = (t & 3) * 8;
  f32x4 acc[8] = {};
  for (int ks = 0; ks < 8; ++ks) {
    const int kc = ks * 32;
    __syncthreads();
    *(f16x8*)&Al[arow][akq] = *(const f16x8*)(A + (size_t)(m0 + arow) * 256 + kc + akq);
#pragma unroll
    for (int hh = 0; hh < 2; ++hh) {
      const int brow = arow + 64 * hh;
      *(f16x8*)&Bl[brow][akq] = *(const f16x8*)(BT + (size_t)brow * 256 + kc + akq);
    }
    __syncthreads();
    f16x8 af = *(const f16x8*)&Al[16 * w + lr][lg * 8];
#pragma unroll
    for (int nt = 0; nt < 8; ++nt) {
      f16x8 bf = *(const f16x8*)&Bl[nt * 16 + lr][lg * 8];
      acc[nt] = __builtin_amdgcn_mfma_f32_16x16x32_f16(af, bf, acc[nt], 0, 0, 0);
    }
  }
  float v[8][4];
#pragma unroll
  for (int nt = 0; nt < 8; ++nt) {
    const float bb = bias[nt * 16 + lr];
#pragma unroll
    for (int r = 0; r < 4; ++r) v[nt][r] = acc[nt][r] + bb;
  }
#pragma unroll
  for (int r = 0; r < 4; ++r) {
    float ss = 0.f;
#pragma unroll
    for (int nt = 0; nt < 8; ++nt) ss += v[nt][r] * v[nt][r];
    ss += __shfl_xor(ss, 1); ss += __shfl_xor(ss, 2); ss += __shfl_xor(ss, 4); ss += __shfl_xor(ss, 8);
    const float scl = 1.f / fmaxf(sqrtf(ss), 1e-12f);
    const int m = m0 + 16 * w + lg * 4 + r;
#pragma unroll
    for (int nt = 0; nt < 8; ++nt) {
      const int n = nt * 16 + lr;
      const float z = v[nt][r] * scl;
      zf32[(size_t)m * 128 + n] = z;
      zf16[(size_t)m * 128 + n] = (f16)z;
    }
  }
}

// ---------------------------------------------------------------------------
// K4: GRU scan, int8 W + sdot4 (R16 version, unchanged).
// ---------------------------------------------------------------------------
__global__ __launch_bounds__(768, 3) void k_gru(const f16* __restrict__ gx, const uint8_t* __restrict__ whhQ,
                                                const float* __restrict__ wsc, const float* __restrict__ bhh,
                                                float* __restrict__ cout, f16* __restrict__ cf16) {
  __shared__ __align__(16) uint32_t h8[2][64];
  __shared__ float rz[2][256];
  const int b = blockIdx.x;
  const int o = threadIdx.x;
  const int g = o >> 8;
  const int c = o & 255;
  const float sc = wsc[o];
  const float bh = bhh[o];
  if (o < 64) { h8[0][o] = 0u; }
  float h_own = 0.f;
  const f16* gxp = gx + (size_t)b * 256 * 768 + o;
  float* coutp = cout + (size_t)b * 256 * 256 + c;
  f16* cfp = cf16 + (size_t)b * 256 * 256 + c;
  const uint8_t* wbase = whhQ + (size_t)o * 16;
  __syncthreads();
#pragma unroll 1
  for (int tt = 0; tt < 256; ++tt) {
    const int cur = tt & 1;
    const float gxv = (float)gxp[tt * 768];
    int i0 = 0, i1 = 0, i2 = 0, i3 = 0;
    const uint4* hp = (const uint4*)(&h8[cur][0]);
#pragma unroll
    for (int jq = 0; jq < 16; ++jq) {
      const uint4 wq = *(const uint4*)(wbase + (size_t)jq * 12288);
      const uint4 hq = hp[jq];
      i0 = __builtin_amdgcn_sdot4((int)wq.x, (int)hq.x, i0, false);
      i1 = __builtin_amdgcn_sdot4((int)wq.y, (int)hq.y, i1, false);
      i2 = __builtin_amdgcn_sdot4((int)wq.z, (int)hq.z, i2, false);
      i3 = __builtin_amdgcn_sdot4((int)wq.w, (int)hq.w, i3, false);
    }
    const float dot = (float)((i0 + i1) + (i2 + i3)) * sc + bh;
    if (g < 2) rz[g][c] = sigm_(gxv + dot);
    __syncthreads();
    if (g == 2) {
      const float r = rz[0][c], zz = rz[1][c];
      const float n = tanh_(gxv + r * dot);
      const float hn = (1.f - zz) * n + zz * h_own;
      h_own = hn;
      const int qh = (int)rintf(hn * 127.f);
      ((uint8_t*)&h8[cur ^ 1][0])[c] = (uint8_t)(int8_t)qh;
      coutp[tt * 256] = hn;
      cfp[tt * 256] = (f16)hn;
    }
    __syncthreads();
  }
}

// ---------------------------------------------------------------------------
// K5 (R18): preds from global c-gathers + 2-phase Wk staging; logits with
// SWAPPED operands (S[s][t] = mfma(z, P)) -> thread-local online LSE.
// LDS: one 34KB buffer (Bl [128][136] -> P [64][136] + comb[256]f4).
// ---------------------------------------------------------------------------
__global__ __launch_bounds__(256) void k_cpc(const f16* __restrict__ cf16, const f16* __restrict__ zf16,
                                             const f16* __restrict__ wkT, const float* __restrict__ wkb,
                                             float* __restrict__ accb) {
  __shared__ __align__(16) char PB[34816];
  f16* Blp = (f16*)PB;                       // [128][136] during preds
  f16* Pp = (f16*)PB;                        // [64][136] after preds
  float4* comb = (float4*)(PB + 17408);      // [256] at the end
  const int kk = blockIdx.x, tc = blockIdx.y, b = blockIdx.z;
  const int t0 = tc * 64;
  const int t = threadIdx.x;
  const int w = t >> 6, l = t & 63, lr = l & 15, hi = l >> 4;
  // ---- preds GEMM: C[t][d] = c[t][:] . wk[d][:], A from global gathers ----
  f32x4 acc[8] = {};
  const f16* cbase = cf16 + ((size_t)b * 256 + t0 + 16 * w + lr) * 256;
#pragma unroll 1
  for (int p = 0; p < 2; ++p) {
    __syncthreads();
    {
      const uint32_t* bsrc = (const uint32_t*)(wkT + ((size_t)kk << 15)) + p * 64;
      uint32_t* bd = (uint32_t*)PB;
#pragma unroll
      for (int it = 0; it < 32; ++it) {
        const int idx = it * 256 + t, row = idx >> 6, cw = idx & 63;
        bd[row * 68 + cw] = bsrc[row * 128 + cw];
      }
    }
    __syncthreads();
#pragma unroll
    for (int ks = 0; ks < 4; ++ks) {
      const f16x8 af = *(const f16x8*)(cbase + p * 128 + ks * 32 + hi * 8);
#pragma unroll
      for (int nt = 0; nt < 8; ++nt) {
        const f16x8 bf = *(const f16x8*)(Blp + (nt * 16 + lr) * 136 + ks * 32 + hi * 8);
        acc[nt] = __builtin_amdgcn_mfma_f32_16x16x32_f16(af, bf, acc[nt], 0, 0, 0);
      }
    }
  }
  __syncthreads();  // all Bl reads complete before P overwrites
  // ---- preds epilogue: bias + row l2norm -> P[t][d] (t-major for B-frag) ----
  {
    float v[8][4];
#pragma unroll
    for (int nt = 0; nt < 8; ++nt) {
      const float bb = wkb[kk * 128 + nt * 16 + lr];
#pragma unroll
      for (int r = 0; r < 4; ++r) v[nt][r] = acc[nt][r] + bb;
    }
#pragma unroll
    for (int r = 0; r < 4; ++r) {
      float ss = 0.f;
#pragma unroll
      for (int nt = 0; nt < 8; ++nt) ss += v[nt][r] * v[nt][r];
      ss += __shfl_xor(ss, 1); ss += __shfl_xor(ss, 2); ss += __shfl_xor(ss, 4); ss += __shfl_xor(ss, 8);
      const float scl = 1.f / fmaxf(sqrtf(ss), 1e-12f);
#pragma unroll
      for (int nt = 0; nt < 8; ++nt)
        Pp[(16 * w + hi * 4 + r) * 136 + nt * 16 + lr] = (f16)(v[nt][r] * scl);
    }
  }
  __syncthreads();
  // ---- logits, swapped: S[s][t] = mfma(z_frag, P_frag). Wave w owns
  // s in [64w, 64w+64); lane owns t-col nt*16+lr, s = sb + 4*hi + r. ----
  float m_[4], l_[4], pos_[4], neg_[4];
#pragma unroll
  for (int nt = 0; nt < 4; ++nt) { m_[nt] = -1e30f; l_[nt] = 0.f; pos_[nt] = -1e30f; neg_[nt] = -1e30f; }
  const f16* zbase = zf16 + (size_t)b * 32768;
#pragma unroll 1
  for (int stile = 0; stile < 4; ++stile) {
    const int sb = 64 * w + 16 * stile;
    f16x8 af[4];
#pragma unroll
    for (int ks = 0; ks < 4; ++ks)
      af[ks] = *(const f16x8*)(zbase + (size_t)(sb + lr) * 128 + ks * 32 + hi * 8);
#pragma unroll
    for (int nt = 0; nt < 4; ++nt) {
      f32x4 sa = {};
#pragma unroll
      for (int ks = 0; ks < 4; ++ks) {
        const f16x8 bf = *(const f16x8*)(Pp + (nt * 16 + lr) * 136 + ks * 32 + hi * 8);
        sa = __builtin_amdgcn_mfma_f32_16x16x32_f16(af[ks], bf, sa, 0, 0, 0);
      }
      const int pos_s = t0 + nt * 16 + lr + kk + 1;
      float vv[4];
#pragma unroll
      for (int r = 0; r < 4; ++r) vv[r] = sa[r] * 10.f;  // 1/TEMP
      const float cm = fmaxf(fmaxf(vv[0], vv[1]), fmaxf(vv[2], vv[3]));
      const float nm = fmaxf(m_[nt], cm);
      const float ps = __expf(vv[0] - nm) + __expf(vv[1] - nm) +
                       __expf(vv[2] - nm) + __expf(vv[3] - nm);
      l_[nt] = l_[nt] * __expf(m_[nt] - nm) + ps;
      m_[nt] = nm;
#pragma unroll
      for (int r = 0; r < 4; ++r) {
        const int s = sb + 4 * hi + r;
        if (s == pos_s) pos_[nt] = vv[r];
        else neg_[nt] = fmaxf(neg_[nt], vv[r]);
      }
    }
  }
  // ---- wave-internal combine over hi groups (2 shfl steps) ----
#pragma unroll
  for (int nt = 0; nt < 4; ++nt) {
#pragma unroll
    for (int d = 16; d <= 32; d <<= 1) {
      const float mo = __shfl_xor(m_[nt], d);
      const float lo = __shfl_xor(l_[nt], d);
      const float po = __shfl_xor(pos_[nt], d);
      const float no = __shfl_xor(neg_[nt], d);
      const float nm = fmaxf(m_[nt], mo);
      l_[nt] = l_[nt] * __expf(m_[nt] - nm) + lo * __expf(mo - nm);
      m_[nt] = nm;
      pos_[nt] = fmaxf(pos_[nt], po);
      neg_[nt] = fmaxf(neg_[nt], no);
    }
    if (l < 16) comb[w * 64 + nt * 16 + lr] = make_float4(m_[nt], l_[nt], pos_[nt], neg_[nt]);
  }
  __syncthreads();
  // ---- final cross-wave combine + block reduce (threads 0..63 = wave 0) ----
  if (t < 64) {
    float M = -1e30f, L = 0.f, PV = -1e30f, NG = -1e30f;
#pragma unroll
    for (int ws = 0; ws < 4; ++ws) {
      const float4 v = comb[ws * 64 + t];
      const float nm = fmaxf(M, v.x);
      L = L * __expf(M - nm) + v.y * __expf(v.x - nm);
      M = nm;
      PV = fmaxf(PV, v.z);
      NG = fmaxf(NG, v.w);
    }
    float lsum = 0.f, csum = 0.f;
    const int trow = t0 + t;
    if (trow < 244) {
      lsum = (M + __logf(L)) - PV;
      csum = (PV >= NG) ? 1.f : 0.f;
    }
    lsum += __shfl_xor(lsum, 1); csum += __shfl_xor(csum, 1);
    lsum += __shfl_xor(lsum, 2); csum += __shfl_xor(csum, 2);
    lsum += __shfl_xor(lsum, 4); csum += __shfl_xor(csum, 4);
    lsum += __shfl_xor(lsum, 8); csum += __shfl_xor(csum, 8);
    lsum += __shfl_xor(lsum, 16); csum += __shfl_xor(csum, 16);
    lsum += __shfl_xor(lsum, 32); csum += __shfl_xor(csum, 32);
    if (t == 0) { atomicAdd(&accb[0], lsum); atomicAdd(&accb[1], csum); }
  }
}

__global__ void k_fin(const float* __restrict__ accb, float* __restrict__ out) {
  out[0] = accb[0] * (1.0f / NTOT_LOSS);
  out[1] = accb[1] * (100.0f / NTOT_LOSS);
}

// ---------------------------------------------------------------------------
extern "C" void kernel_launch(void* const* d_in, const int* in_sizes, int n_in,
                              void* d_out, int out_size, void* d_ws, size_t ws_size,
                              hipStream_t stream) {
  (void)in_sizes; (void)n_in; (void)out_size; (void)ws_size;
  const float* rr  = (const float*)d_in[0];
  const float* w1  = (const float*)d_in[1];
  const float* b1  = (const float*)d_in[2];
  const float* w2  = (const float*)d_in[3];
  const float* b2  = (const float*)d_in[4];
  const float* wih = (const float*)d_in[5];
  const float* whh = (const float*)d_in[6];
  const float* bih = (const float*)d_in[7];
  const float* bhh = (const float*)d_in[8];
  const float* wkw = (const float*)d_in[9];
  const float* wkb = (const float*)d_in[10];
  float* out = (float*)d_out;
  char* ws = (char*)d_ws;

  const size_t GX_B = (size_t)32768 * 768 * 2;  // 50,331,648
  f16* gx   = (f16*)ws;
  f16* h1   = (f16*)ws;  // alias: h1 dead before gx written
  f16* zf16 = (f16*)(ws + GX_B);
  f16* cf16 = (f16*)(ws + GX_B + 8388608);
  f16* w1T  = (f16*)(ws + GX_B + 8388608 + 16777216);
  f16* w2T  = w1T + 65536;
  f16* wihF = w2T + 32768;
  uint8_t* whhQ = (uint8_t*)(wihF + 98304);
  float* wsc = (float*)(whhQ + 196608);
  f16* wkT  = (f16*)(wsc + 768);
  float* accb = (float*)(wkT + 393216);

  float* zf32 = out + 2;
  float* cf32 = out + 2 + 4194304;

  k_prep<<<256, 256, 0, stream>>>(w1, w2, wih, whh, wkw, w1T, w2T, wihF, whhQ, wsc, wkT, accb);
  k_gemm64<256, true, true><<<dim3(512, 4), 256, 0, stream>>>(rr, w1T, b1, h1, 256);
  k_enc2<<<dim3(512), 256, 0, stream>>>(h1, w2T, b2, zf32, zf16);
  k_gemm64<128, false, false><<<dim3(512, 12), 256, 0, stream>>>(zf16, wihF, bih, gx, 768);
  k_gru<<<128, 768, 0, stream>>>(gx, whhQ, wsc, bhh, cf32, cf16);
  k_cpc<<<dim3(12, 4, 128), 256, 0, stream>>>(cf16, zf16, wkT, wkb, accb);
  k_fin<<<1, 1, 0, stream>>>(accb, out);
}